// Round 2
// baseline (688.675 us; speedup 1.0000x reference)
//
#include <hip/hip_runtime.h>

#define NEGF  (-1e30f)
#define LOG2E 1.4426950408889634f
#define LN2F  0.6931471805599453f

constexpr int PF = 16;           // LDS ring slots (steps of prefetch)

__device__ __forceinline__ float fexp2(float x) { return exp2f(x); }
__device__ __forceinline__ float flog2(float x) { return log2f(x); }
__device__ __forceinline__ float lse2(float a, float b) {
    float m  = fmaxf(a, b);
    float mn = fminf(a, b);
    return m + flog2(1.0f + fexp2(mn - m));
}
__device__ __forceinline__ float lse3(float a, float b, float c) {
    float m = fmaxf(fmaxf(a, b), c);
    float s = fexp2(a - m) + fexp2(b - m) + fexp2(c - m);
    return m + flog2(s);
}

// async 16B/lane global -> LDS (HW scatters lane i to lptr + 16*i)
__device__ __forceinline__ void async_copy16(const float* g, float* l) {
    __builtin_amdgcn_global_load_lds(
        (const __attribute__((address_space(1))) void*)g,
        (__attribute__((address_space(3))) void*)l, 16, 0, 0);
}

// ---------------------------------------------------------------------------
// Gather emissions for a chunk of steps into em rows of 64 x float4:
//   lane i of row (g,n): [ lp[row][n][0], lp[row][n][tgt(2i)], lp[row][n][tgt(2i+1)], 0 ] * LOG2E
// fwd rows: t = g0+g+1 ; bwd rows: t = len_in[n]-1-(g0+g)
// ---------------------------------------------------------------------------
__global__ void ctc_gather(const float* __restrict__ lp, const int* __restrict__ tgt,
                           const int* __restrict__ ilen, const int* __restrict__ tlen,
                           float* __restrict__ em_f, float* __restrict__ em_b,
                           int g0, int CRlen, int T, int N, int C, int L)
{
    const int widx = (blockIdx.x * blockDim.x + threadIdx.x) >> 6;
    const int lane = threadIdx.x & 63;
    const int total = 2 * CRlen * N;
    if (widx >= total) return;
    const bool is_fwd = widx < CRlen * N;
    const int r = is_fwd ? widx : (widx - CRlen * N);
    const int g = r / N;
    const int n = r - g * N;
    const int len_t  = tlen[n];
    const int len_in = ilen[n];
    int row;
    if (is_fwd) { row = g0 + g + 1; if (row > T - 1) row = T - 1; }
    else        { row = len_in - 1 - (g0 + g); if (row < 0) row = 0; }
    const int k1 = 2 * lane, k2 = 2 * lane + 1;
    const int c1 = (k1 < len_t) ? tgt[(size_t)n * L + k1] : 0;
    const int c3 = (k2 < len_t) ? tgt[(size_t)n * L + k2] : 0;
    const float* src = lp + ((size_t)row * N + n) * C;
    const float eb = src[0]  * LOG2E;
    const float e1 = src[c1] * LOG2E;
    const float e3 = src[c3] * LOG2E;
    float* dst = (is_fwd ? em_f : em_b) + ((size_t)g * N + n) * 256 + lane * 4;
    *(float4*)dst = make_float4(eb, e1, e3, 0.0f);
}

// ---------------------------------------------------------------------------
// Serial scan over a chunk. One wave per (direction, utterance); lane i owns
// extended states 4i..4i+3. Emissions streamed via global_load_lds ring.
// ---------------------------------------------------------------------------
__global__ __launch_bounds__(64, 1)
void ctc_scan(const float* __restrict__ lp, const int* __restrict__ tgt,
              const int* __restrict__ ilen, const int* __restrict__ tlen,
              const float* __restrict__ em_f, const float* __restrict__ em_b,
              float* __restrict__ state,     // [2N][256] floats
              int g0, int CRlen, int first, int T, int N, int C, int L)
{
    __shared__ float ring[PF * 256];          // 16 KB: PF slots x 64 lanes x float4

    const int  b      = blockIdx.x;
    const bool is_fwd = (b < N);
    const int  n      = is_fwd ? b : (b - N);
    const int  lane   = threadIdx.x;
    const int  len_t  = tlen[n];
    const int  len_in = ilen[n];
    const int  tm     = (len_in - 1) >> 1;
    const int  send   = 2 * len_t;

    const size_t tb = (size_t)n * L;
    auto getT = [&](int k) -> int {
        return (k >= 0 && k < len_t) ? tgt[tb + k] : 0;
    };
    const int lm1 = getT(2 * lane - 1);
    const int l1  = getT(2 * lane);
    const int l2  = getT(2 * lane + 1);
    const int l3  = getT(2 * lane + 2);
    const bool skip1 = (lane > 0) && (l1 != lm1);
    const bool skip3 = (l2 != l1);
    const bool skip5 = (l3 != l2);
    const int  s0 = 4 * lane;
    const bool v0 = (s0     <= send);
    const bool v1 = (s0 + 1 <= send);
    const bool v2 = (s0 + 2 <= send);
    const bool v3 = (s0 + 3 <= send);

    float* strow = state + ((size_t)(is_fwd ? 0 : N) + n) * 256;

    float a0, a1, a2, a3;
    if (first) {
        if (is_fwd) {
            const float eb0 = lp[(size_t)n * C] * LOG2E;
            const int   cl0 = (0 < len_t) ? tgt[tb] : 0;
            const float e10 = lp[(size_t)n * C + cl0] * LOG2E;
            a0 = (lane == 0)              ? eb0 : NEGF;
            a1 = (lane == 0 && 1 <= send) ? e10 : NEGF;
            a2 = NEGF; a3 = NEGF;
            a0 = v0 ? a0 : NEGF; a1 = v1 ? a1 : NEGF;
        } else {
            a0 = (s0     == send || s0     == send - 1) ? 0.0f : NEGF;
            a1 = (s0 + 1 == send || s0 + 1 == send - 1) ? 0.0f : NEGF;
            a2 = (s0 + 2 == send || s0 + 2 == send - 1) ? 0.0f : NEGF;
            a3 = (s0 + 3 == send || s0 + 3 == send - 1) ? 0.0f : NEGF;
            a0 = v0 ? a0 : NEGF; a1 = v1 ? a1 : NEGF;
            a2 = v2 ? a2 : NEGF; a3 = v3 ? a3 : NEGF;
        }
    } else {
        float4 st = *((const float4*)strow + lane);
        a0 = st.x; a1 = st.y; a2 = st.z; a3 = st.w;
    }

    const int nsteps_total = is_fwd ? tm : (len_in - 1 - tm);
    int rem = nsteps_total - g0;
    const int lim = (rem < CRlen) ? rem : CRlen;   // active steps this chunk

    const float* emw = (is_fwd ? em_f : em_b) + (size_t)n * 256;
    const size_t rowstride = (size_t)N * 256;

    // make sure no stray vm ops are outstanding before the counted pipeline
    asm volatile("s_waitcnt vmcnt(0)" ::: "memory");

    // prologue: issue loads for chunk-local steps 0..PF-2 into slots 0..PF-2
    #pragma unroll
    for (int j = 0; j < PF - 1; ++j) {
        int gl = j; if (gl > CRlen - 1) gl = CRlen - 1;
        async_copy16(emw + (size_t)gl * rowstride + lane * 4, &ring[j * 256]);
    }
    asm volatile("s_waitcnt vmcnt(14)" ::: "memory");   // step 0 landed
    float4 ecur = *(const float4*)&ring[0 * 256 + lane * 4];
    asm volatile("s_waitcnt lgkmcnt(0)" ::: "memory");

    for (int sb = 0; sb < CRlen; sb += PF) {
        #pragma unroll
        for (int j = 0; j < PF; ++j) {
            const int scur = sb + j;
            // wait until step scur+1's load has landed (issue #scur+1)
            asm volatile("s_waitcnt vmcnt(13)" ::: "memory");
            const int jn = (j + 1) & (PF - 1);
            float4 enext = *(const float4*)&ring[jn * 256 + lane * 4];

            const bool act = scur < lim;
            if (is_fwd) {
                float p3 = __shfl_up(a3, 1, 64);
                p3 = (lane == 0) ? NEGF : p3;
                float n0 = lse2(a0, p3) + ecur.x;
                float n1 = lse3(a1, a0, skip1 ? p3 : NEGF) + ecur.y;
                float n2 = lse2(a2, a1) + ecur.x;
                float n3 = lse3(a3, a2, skip3 ? a1 : NEGF) + ecur.z;
                a0 = (act && v0) ? n0 : a0;
                a1 = (act && v1) ? n1 : a1;
                a2 = (act && v2) ? n2 : a2;
                a3 = (act && v3) ? n3 : a3;
            } else {
                float f0 = a0 + ecur.x;
                float f1 = a1 + ecur.y;
                float f2 = a2 + ecur.x;
                float f3 = a3 + ecur.z;
                float f0p = __shfl_down(f0, 1, 64);
                float f1p = __shfl_down(f1, 1, 64);
                f0p = (lane == 63) ? NEGF : f0p;
                f1p = (lane == 63) ? NEGF : f1p;
                float n0 = lse2(f0, f1);
                float n1 = lse3(f1, f2, skip3 ? f3 : NEGF);
                float n2 = lse2(f2, f3);
                float n3 = lse3(f3, f0p, skip5 ? f1p : NEGF);
                a0 = (act && v0) ? n0 : a0;
                a1 = (act && v1) ? n1 : a1;
                a2 = (act && v2) ? n2 : a2;
                a3 = (act && v3) ? n3 : a3;
            }

            // all LDS reads (incl. enext) drained before refilling a slot
            asm volatile("s_waitcnt lgkmcnt(0)" ::: "memory");
            int gl = scur + PF - 1; if (gl > CRlen - 1) gl = CRlen - 1;
            const int js = (j + PF - 1) & (PF - 1);
            async_copy16(emw + (size_t)gl * rowstride + lane * 4, &ring[js * 256]);

            ecur = enext;
        }
    }

    *((float4*)strow + lane) = make_float4(a0, a1, a2, a3);
}

// tot_n = logsumexp_s( alpha[tm][s] + beta[tm][s] );  out += -tot_n if finite
__global__ __launch_bounds__(64, 1)
void ctc_combine(const float* __restrict__ state, float* __restrict__ out, int N)
{
    const int n = blockIdx.x;
    const int lane = threadIdx.x;
    const float4 A = *((const float4*)(state + (size_t)n * 256) + lane);
    const float4 B = *((const float4*)(state + (size_t)(N + n) * 256) + lane);
    float v = lse2(lse2(A.x + B.x, A.y + B.y), lse2(A.z + B.z, A.w + B.w));
    #pragma unroll
    for (int off = 1; off < 64; off <<= 1) {
        float o = __shfl_xor(v, off, 64);
        v = lse2(v, o);
    }
    if (lane == 0) {
        float tot = v * LN2F;
        if (tot > -1e29f) atomicAdd(out, -tot);
    }
}

extern "C" void kernel_launch(void* const* d_in, const int* in_sizes, int n_in,
                              void* d_out, int out_size, void* d_ws, size_t ws_size,
                              hipStream_t stream) {
    const float* lp      = (const float*)d_in[0];
    const int*   targets = (const int*)d_in[1];
    const int*   in_len  = (const int*)d_in[2];
    const int*   tgt_len = (const int*)d_in[3];
    const int N = in_sizes[2];
    const int L = in_sizes[1] / N;
    const int C = 1024;                       // fixed by the reference problem
    const int T = (int)((long)in_sizes[0] / ((long)N * C));

    float* out   = (float*)d_out;
    float* state = (float*)d_ws;              // [2N][256] floats = 64 KB
    const size_t state_bytes = (size_t)2 * N * 256 * sizeof(float);

    const int G = (T + 1) / 2;                // max serial steps per direction
    size_t avail = (ws_size > state_bytes) ? (ws_size - state_bytes) : 0;
    int CR = (int)(avail / ((size_t)2 * N * 256 * sizeof(float)));
    if (CR < 1) CR = 1;
    if (CR > G) CR = G;
    const int nsuper = (G + CR - 1) / CR;

    float* em_f = state + (size_t)2 * N * 256;
    float* em_b = em_f + (size_t)CR * N * 256;

    hipMemsetAsync(out, 0, sizeof(float), stream);
    for (int c = 0; c < nsuper; ++c) {
        const int g0 = c * CR;
        int CRlen = G - g0; if (CRlen > CR) CRlen = CR;
        const int waves  = 2 * CRlen * N;
        const int blocks = (waves * 64 + 255) / 256;
        ctc_gather<<<blocks, 256, 0, stream>>>(lp, targets, in_len, tgt_len,
                                               em_f, em_b, g0, CRlen, T, N, C, L);
        ctc_scan<<<2 * N, 64, 0, stream>>>(lp, targets, in_len, tgt_len,
                                           em_f, em_b, state,
                                           g0, CRlen, (c == 0) ? 1 : 0, T, N, C, L);
    }
    ctc_combine<<<N, 64, 0, stream>>>(state, out, N);
}

// Round 3
// 506.446 us; speedup vs baseline: 1.3598x; 1.3598x over previous
//
#include <hip/hip_runtime.h>

#define NEGF  (-1e30f)
#define LOG2E 1.4426950408889634f
#define LN2F  0.6931471805599453f

constexpr int D = 16;            // register prefetch depth (steps)

__device__ __forceinline__ float lse2(float a, float b) {
    float m  = fmaxf(a, b);
    float mn = fminf(a, b);
    return m + log2f(1.0f + exp2f(mn - m));
}
__device__ __forceinline__ float lse3(float a, float b, float c) {
    float m = fmaxf(fmaxf(a, b), c);
    float s = exp2f(a - m) + exp2f(b - m) + exp2f(c - m);
    return m + log2f(s);
}

// cross-lane shift by 1 via DPP (VALU latency, no LDS on the serial chain)
// wave_shr:1 (0x138): lane i <- lane i-1 ; lane 0 <- fill   (shfl_up 1)
// wave_shl:1 (0x130): lane i <- lane i+1 ; lane 63 <- fill  (shfl_down 1)
__device__ __forceinline__ float dpp_up1(float x, float fill) {
    int r = __builtin_amdgcn_update_dpp(__float_as_int(fill), __float_as_int(x),
                                        0x138, 0xF, 0xF, false);
    return __int_as_float(r);
}
__device__ __forceinline__ float dpp_down1(float x, float fill) {
    int r = __builtin_amdgcn_update_dpp(__float_as_int(fill), __float_as_int(x),
                                        0x130, 0xF, 0xF, false);
    return __int_as_float(r);
}

// ---------------------------------------------------------------------------
// Gather emissions for a chunk of steps:
//   em2[g][n][lane] = float2( lp[row][n][tgt(2*lane)], lp[row][n][tgt(2*lane+1)] ) * LOG2E
//   eb [g][n]       = lp[row][n][0] * LOG2E
// fwd rows: t = g0+g+1 ; bwd rows: t = len_in[n]-1-(g0+g)
// ---------------------------------------------------------------------------
__global__ void ctc_gather(const float* __restrict__ lp, const int* __restrict__ tgt,
                           const int* __restrict__ ilen, const int* __restrict__ tlen,
                           float2* __restrict__ em_f2, float2* __restrict__ em_b2,
                           float* __restrict__ eb_f, float* __restrict__ eb_b,
                           int g0, int CRlen, int T, int N, int C, int L)
{
    const int widx = (blockIdx.x * blockDim.x + threadIdx.x) >> 6;
    const int lane = threadIdx.x & 63;
    const int total = 2 * CRlen * N;
    if (widx >= total) return;
    const bool is_fwd = widx < CRlen * N;
    const int r = is_fwd ? widx : (widx - CRlen * N);
    const int g = r / N;
    const int n = r - g * N;
    const int len_t  = tlen[n];
    const int len_in = ilen[n];
    int row;
    if (is_fwd) { row = g0 + g + 1; if (row > T - 1) row = T - 1; }
    else        { row = len_in - 1 - (g0 + g); if (row < 0) row = 0; }
    const int k1 = 2 * lane, k2 = 2 * lane + 1;
    const int c1 = (k1 < len_t) ? tgt[(size_t)n * L + k1] : 0;
    const int c3 = (k2 < len_t) ? tgt[(size_t)n * L + k2] : 0;
    const float* src = lp + ((size_t)row * N + n) * C;
    const float e1 = src[c1] * LOG2E;
    const float e3 = src[c3] * LOG2E;
    float2* dst2 = (is_fwd ? em_f2 : em_b2) + ((size_t)g * N + n) * 64 + lane;
    *dst2 = make_float2(e1, e3);
    if (lane == 0)
        (is_fwd ? eb_f : eb_b)[(size_t)g * N + n] = src[0] * LOG2E;
}

// ---------------------------------------------------------------------------
// Serial scan over a chunk. One wave per (direction, utterance); lane i owns
// extended states 4i..4i+3. Emissions streamed through a 16-deep register
// pipeline of plain loads; cross-lane via DPP.
// ---------------------------------------------------------------------------
__global__ __launch_bounds__(64, 1)
void ctc_scan(const float* __restrict__ lp, const int* __restrict__ tgt,
              const int* __restrict__ ilen, const int* __restrict__ tlen,
              const float2* __restrict__ em_f2, const float2* __restrict__ em_b2,
              const float* __restrict__ eb_f, const float* __restrict__ eb_b,
              float* __restrict__ state,     // [2N][256] floats
              int g0, int CRlen, int first, int T, int N, int C, int L)
{
    const int  b      = blockIdx.x;
    const bool is_fwd = (b < N);
    const int  n      = is_fwd ? b : (b - N);
    const int  lane   = threadIdx.x;
    const int  len_t  = tlen[n];
    const int  len_in = ilen[n];
    const int  tm     = (len_in - 1) >> 1;
    const int  send   = 2 * len_t;

    const size_t tb = (size_t)n * L;
    auto getT = [&](int k) -> int {
        return (k >= 0 && k < len_t) ? tgt[tb + k] : 0;
    };
    const int lm1 = getT(2 * lane - 1);
    const int l1  = getT(2 * lane);
    const int l2  = getT(2 * lane + 1);
    const int l3  = getT(2 * lane + 2);
    const bool skip1 = (lane > 0) && (l1 != lm1);
    const bool skip3 = (l2 != l1);
    const bool skip5 = (l3 != l2);
    const int  s0 = 4 * lane;
    const bool v0 = (s0     <= send);
    const bool v1 = (s0 + 1 <= send);
    const bool v2 = (s0 + 2 <= send);
    const bool v3 = (s0 + 3 <= send);

    float* strow = state + ((size_t)(is_fwd ? 0 : N) + n) * 256;

    float a0, a1, a2, a3;
    if (first) {
        if (is_fwd) {
            const float eb0 = lp[(size_t)n * C] * LOG2E;
            const int   cl0 = (0 < len_t) ? tgt[tb] : 0;
            const float e10 = lp[(size_t)n * C + cl0] * LOG2E;
            a0 = (lane == 0)              ? eb0 : NEGF;
            a1 = (lane == 0 && 1 <= send) ? e10 : NEGF;
            a2 = NEGF; a3 = NEGF;
            a0 = v0 ? a0 : NEGF; a1 = v1 ? a1 : NEGF;
        } else {
            a0 = (s0     == send || s0     == send - 1) ? 0.0f : NEGF;
            a1 = (s0 + 1 == send || s0 + 1 == send - 1) ? 0.0f : NEGF;
            a2 = (s0 + 2 == send || s0 + 2 == send - 1) ? 0.0f : NEGF;
            a3 = (s0 + 3 == send || s0 + 3 == send - 1) ? 0.0f : NEGF;
            a0 = v0 ? a0 : NEGF; a1 = v1 ? a1 : NEGF;
            a2 = v2 ? a2 : NEGF; a3 = v3 ? a3 : NEGF;
        }
    } else {
        float4 st = *((const float4*)strow + lane);
        a0 = st.x; a1 = st.y; a2 = st.z; a3 = st.w;
    }

    const int nsteps_total = is_fwd ? tm : (len_in - 1 - tm);
    int rem = nsteps_total - g0;
    const int lim = (rem < CRlen) ? rem : CRlen;   // active steps this chunk

    const float2* ew  = (is_fwd ? em_f2 : em_b2) + (size_t)n * 64 + lane;
    const float*  ebw = (is_fwd ? eb_f  : eb_b ) + n;
    const size_t  rs2 = (size_t)N * 64;            // float2 stride per step
    const size_t  rs1 = (size_t)N;                 // float  stride per step

    float2 pe[D]; float pb[D];
    #pragma unroll
    for (int j = 0; j < D; ++j) {
        int r = j; if (r > CRlen - 1) r = CRlen - 1;
        pe[j] = ew[(size_t)r * rs2];
        pb[j] = ebw[(size_t)r * rs1];
    }

    for (int g = 0; g < CRlen; g += D) {
        #pragma unroll
        for (int j = 0; j < D; ++j) {
            const int scur = g + j;
            const bool act = scur < lim;
            const float eb = pb[j], e1 = pe[j].x, e3 = pe[j].y;

            if (is_fwd) {
                float p3 = dpp_up1(a3, NEGF);
                float n0 = lse2(a0, p3) + eb;
                float n1 = lse3(a1, a0, skip1 ? p3 : NEGF) + e1;
                float n2 = lse2(a2, a1) + eb;
                float n3 = lse3(a3, a2, skip3 ? a1 : NEGF) + e3;
                a0 = (act && v0) ? n0 : a0;
                a1 = (act && v1) ? n1 : a1;
                a2 = (act && v2) ? n2 : a2;
                a3 = (act && v3) ? n3 : a3;
            } else {
                float f0 = a0 + eb;
                float f1 = a1 + e1;
                float f2 = a2 + eb;
                float f3 = a3 + e3;
                float f0p = dpp_down1(f0, NEGF);
                float f1p = dpp_down1(f1, NEGF);
                float n0 = lse2(f0, f1);
                float n1 = lse3(f1, f2, skip3 ? f3 : NEGF);
                float n2 = lse2(f2, f3);
                float n3 = lse3(f3, f0p, skip5 ? f1p : NEGF);
                a0 = (act && v0) ? n0 : a0;
                a1 = (act && v1) ? n1 : a1;
                a2 = (act && v2) ? n2 : a2;
                a3 = (act && v3) ? n3 : a3;
            }

            int r = scur + D; if (r > CRlen - 1) r = CRlen - 1;
            pe[j] = ew[(size_t)r * rs2];
            pb[j] = ebw[(size_t)r * rs1];
        }
    }

    *((float4*)strow + lane) = make_float4(a0, a1, a2, a3);
}

// tot_n = logsumexp_s( alpha[tm][s] + beta[tm][s] );  out += -tot_n if finite
__global__ __launch_bounds__(64, 1)
void ctc_combine(const float* __restrict__ state, float* __restrict__ out, int N)
{
    const int n = blockIdx.x;
    const int lane = threadIdx.x;
    const float4 A = *((const float4*)(state + (size_t)n * 256) + lane);
    const float4 B = *((const float4*)(state + (size_t)(N + n) * 256) + lane);
    float v = lse2(lse2(A.x + B.x, A.y + B.y), lse2(A.z + B.z, A.w + B.w));
    #pragma unroll
    for (int off = 1; off < 64; off <<= 1) {
        float o = __shfl_xor(v, off, 64);
        v = lse2(v, o);
    }
    if (lane == 0) {
        float tot = v * LN2F;
        if (tot > -1e29f) atomicAdd(out, -tot);
    }
}

extern "C" void kernel_launch(void* const* d_in, const int* in_sizes, int n_in,
                              void* d_out, int out_size, void* d_ws, size_t ws_size,
                              hipStream_t stream) {
    const float* lp      = (const float*)d_in[0];
    const int*   targets = (const int*)d_in[1];
    const int*   in_len  = (const int*)d_in[2];
    const int*   tgt_len = (const int*)d_in[3];
    const int N = in_sizes[2];
    const int L = in_sizes[1] / N;
    const int C = 1024;                       // fixed by the reference problem
    const int T = (int)((long)in_sizes[0] / ((long)N * C));

    float* out   = (float*)d_out;
    float* state = (float*)d_ws;              // [2N][256] floats = 64 KB
    const size_t state_bytes = (size_t)2 * N * 256 * sizeof(float);

    const int G = (T + 1) / 2;                // max serial steps per direction
    size_t avail = (ws_size > state_bytes) ? (ws_size - state_bytes) : 0;
    // per chunk-step per direction: N*(64*8 + 4) bytes
    int CR = (int)(avail / ((size_t)2 * N * (64 * 8 + 8)));
    if (CR < 1) CR = 1;
    if (CR > G) CR = G;
    const int nsuper = (G + CR - 1) / CR;

    float2* em_f2 = (float2*)(state + (size_t)2 * N * 256);
    float2* em_b2 = em_f2 + (size_t)CR * N * 64;
    float*  eb_f  = (float*)(em_b2 + (size_t)CR * N * 64);
    float*  eb_b  = eb_f + (size_t)CR * N;

    hipMemsetAsync(out, 0, sizeof(float), stream);
    for (int c = 0; c < nsuper; ++c) {
        const int g0 = c * CR;
        int CRlen = G - g0; if (CRlen > CR) CRlen = CR;
        const int waves  = 2 * CRlen * N;
        const int blocks = (waves * 64 + 255) / 256;
        ctc_gather<<<blocks, 256, 0, stream>>>(lp, targets, in_len, tgt_len,
                                               em_f2, em_b2, eb_f, eb_b,
                                               g0, CRlen, T, N, C, L);
        ctc_scan<<<2 * N, 64, 0, stream>>>(lp, targets, in_len, tgt_len,
                                           em_f2, em_b2, eb_f, eb_b, state,
                                           g0, CRlen, (c == 0) ? 1 : 0, T, N, C, L);
    }
    ctc_combine<<<N, 64, 0, stream>>>(state, out, N);
}

// Round 4
// 498.450 us; speedup vs baseline: 1.3816x; 1.0160x over previous
//
#include <hip/hip_runtime.h>

#define NEGF  (-1e30f)
#define LOG2E 1.4426950408889634f
#define LN2F  0.6931471805599453f

constexpr int BLK = 96;          // steps per LDS refill block

__device__ __forceinline__ float lse2(float a, float b) {
    float m  = fmaxf(a, b);
    float mn = fminf(a, b);
    return m + log2f(1.0f + exp2f(mn - m));
}
__device__ __forceinline__ float lse3(float a, float b, float c) {
    float m = fmaxf(fmaxf(a, b), c);
    float s = exp2f(a - m) + exp2f(b - m) + exp2f(c - m);
    return m + log2f(s);
}

// cross-lane shift by 1 via DPP (VALU latency, no LDS on the serial chain)
__device__ __forceinline__ float dpp_up1(float x, float fill) {
    int r = __builtin_amdgcn_update_dpp(__float_as_int(fill), __float_as_int(x),
                                        0x138, 0xF, 0xF, false);  // wave_shr:1
    return __int_as_float(r);
}
__device__ __forceinline__ float dpp_down1(float x, float fill) {
    int r = __builtin_amdgcn_update_dpp(__float_as_int(fill), __float_as_int(x),
                                        0x130, 0xF, 0xF, false);  // wave_shl:1
    return __int_as_float(r);
}

__device__ __forceinline__ void async16(const void* g, void* l) {
    __builtin_amdgcn_global_load_lds(
        (const __attribute__((address_space(1))) void*)g,
        (__attribute__((address_space(3))) void*)l, 16, 0, 0);
}
__device__ __forceinline__ void async4(const void* g, void* l) {
    __builtin_amdgcn_global_load_lds(
        (const __attribute__((address_space(1))) void*)g,
        (__attribute__((address_space(3))) void*)l, 4, 0, 0);
}

// ---------------------------------------------------------------------------
// Gather emissions for a chunk of steps, per-utterance step-major layout:
//   em2[(n*CRcap + g)*64 + lane] = ( lp[row][n][tgt(2l)], lp[row][n][tgt(2l+1)] )*LOG2E
//   eb [ n*CRcap + g ]           =   lp[row][n][0] * LOG2E
// fwd rows: t = g0+g+1 ; bwd rows: t = len_in[n]-1-(g0+g)
// ---------------------------------------------------------------------------
__global__ void ctc_gather(const float* __restrict__ lp, const int* __restrict__ tgt,
                           const int* __restrict__ ilen, const int* __restrict__ tlen,
                           float2* __restrict__ em_f2, float2* __restrict__ em_b2,
                           float* __restrict__ eb_f, float* __restrict__ eb_b,
                           int g0, int CRlen, int CRcap, int T, int N, int C, int L)
{
    const int widx = (blockIdx.x * blockDim.x + threadIdx.x) >> 6;
    const int lane = threadIdx.x & 63;
    const int total = 2 * CRlen * N;
    if (widx >= total) return;
    const bool is_fwd = widx < CRlen * N;
    const int r = is_fwd ? widx : (widx - CRlen * N);
    const int g = r / N;
    const int n = r - g * N;
    const int len_t  = tlen[n];
    const int len_in = ilen[n];
    int row;
    if (is_fwd) { row = g0 + g + 1; if (row > T - 1) row = T - 1; }
    else        { row = len_in - 1 - (g0 + g); if (row < 0) row = 0; }
    const int k1 = 2 * lane, k2 = 2 * lane + 1;
    const int c1 = (k1 < len_t) ? tgt[(size_t)n * L + k1] : 0;
    const int c3 = (k2 < len_t) ? tgt[(size_t)n * L + k2] : 0;
    const float* src = lp + ((size_t)row * N + n) * C;
    const float e1 = src[c1] * LOG2E;
    const float e3 = src[c3] * LOG2E;
    float2* dst2 = (is_fwd ? em_f2 : em_b2) + ((size_t)n * CRcap + g) * 64 + lane;
    *dst2 = make_float2(e1, e3);
    if (lane == 0)
        (is_fwd ? eb_f : eb_b)[(size_t)n * CRcap + g] = src[0] * LOG2E;
}

// ---------------------------------------------------------------------------
// Serial scan. One wave per (direction, utterance); lane i owns states
// 4i..4i+3. Emissions DMA'd to LDS in 96-step blocks (one vmcnt(0)/block),
// then the 96 steps read only LDS (compiler pipelines ds_read via lgkmcnt).
// ---------------------------------------------------------------------------
__global__ __launch_bounds__(64, 1)
void ctc_scan(const float* __restrict__ lp, const int* __restrict__ tgt,
              const int* __restrict__ ilen, const int* __restrict__ tlen,
              const float2* __restrict__ em_f2, const float2* __restrict__ em_b2,
              const float* __restrict__ eb_f, const float* __restrict__ eb_b,
              float* __restrict__ state,     // [2N][256] floats
              int g0, int CRlen, int CRcap, int first, int T, int N, int C, int L)
{
    __shared__ float2 ldsE[BLK * 64];        // 48 KB emission block
    __shared__ float  ldsB[128];             // blanks (+scatter pad)

    const int  b      = blockIdx.x;
    const bool is_fwd = (b < N);
    const int  n      = is_fwd ? b : (b - N);
    const int  lane   = threadIdx.x;
    const int  len_t  = tlen[n];
    const int  len_in = ilen[n];
    const int  tm     = (len_in - 1) >> 1;
    const int  send   = 2 * len_t;

    const size_t tb = (size_t)n * L;
    auto getT = [&](int k) -> int {
        return (k >= 0 && k < len_t) ? tgt[tb + k] : 0;
    };
    const int lm1 = getT(2 * lane - 1);
    const int l1  = getT(2 * lane);
    const int l2  = getT(2 * lane + 1);
    const int l3  = getT(2 * lane + 2);
    const bool skip1 = (lane > 0) && (l1 != lm1);
    const bool skip3 = (l2 != l1);
    const bool skip5 = (l3 != l2);
    const int  s0 = 4 * lane;
    const bool v0 = (s0     <= send);
    const bool v1 = (s0 + 1 <= send);
    const bool v2 = (s0 + 2 <= send);
    const bool v3 = (s0 + 3 <= send);

    float* strow = state + ((size_t)(is_fwd ? 0 : N) + n) * 256;

    float a0, a1, a2, a3;
    if (first) {
        if (is_fwd) {
            const float eb0 = lp[(size_t)n * C] * LOG2E;
            const int   cl0 = (0 < len_t) ? tgt[tb] : 0;
            const float e10 = lp[(size_t)n * C + cl0] * LOG2E;
            a0 = (lane == 0)              ? eb0 : NEGF;
            a1 = (lane == 0 && 1 <= send) ? e10 : NEGF;
            a2 = NEGF; a3 = NEGF;
            a0 = v0 ? a0 : NEGF; a1 = v1 ? a1 : NEGF;
        } else {
            a0 = (s0     == send || s0     == send - 1) ? 0.0f : NEGF;
            a1 = (s0 + 1 == send || s0 + 1 == send - 1) ? 0.0f : NEGF;
            a2 = (s0 + 2 == send || s0 + 2 == send - 1) ? 0.0f : NEGF;
            a3 = (s0 + 3 == send || s0 + 3 == send - 1) ? 0.0f : NEGF;
            a0 = v0 ? a0 : NEGF; a1 = v1 ? a1 : NEGF;
            a2 = v2 ? a2 : NEGF; a3 = v3 ? a3 : NEGF;
        }
    } else {
        float4 st = *((const float4*)strow + lane);
        a0 = st.x; a1 = st.y; a2 = st.z; a3 = st.w;
    }

    const int nsteps_total = is_fwd ? tm : (len_in - 1 - tm);
    int rem = nsteps_total - g0;
    const int lim = (rem < CRlen) ? rem : CRlen;   // active steps this chunk

    const char*  ewn = (const char*)((is_fwd ? em_f2 : em_b2) + (size_t)n * CRcap * 64);
    const float* bwn = (is_fwd ? eb_f : eb_b) + (size_t)n * CRcap;

    for (int sb = 0; sb < CRlen; sb += BLK) {
        // ---- bulk refill: 96 steps (48 KB) via LDS-DMA, one drain ----
        const char* src = ewn + (size_t)sb * 512;
        #pragma unroll
        for (int i = 0; i < BLK / 2; ++i)
            async16(src + (size_t)i * 1024 + (size_t)lane * 16,
                    (char*)ldsE + i * 1024);
        async4(bwn + sb + lane,      &ldsB[0]);
        async4(bwn + sb + 64 + lane, &ldsB[64]);
        asm volatile("s_waitcnt vmcnt(0)" ::: "memory");

        // ---- compute 96 steps from LDS (predicated past lim) ----
        #pragma unroll 16
        for (int s = 0; s < BLK; ++s) {
            const bool  act = (sb + s) < lim;
            const float2 e  = ldsE[s * 64 + lane];
            const float  eb = ldsB[s];
            if (is_fwd) {
                float p3 = dpp_up1(a3, NEGF);
                float n0 = lse2(a0, p3) + eb;
                float n1 = lse3(a1, a0, skip1 ? p3 : NEGF) + e.x;
                float n2 = lse2(a2, a1) + eb;
                float n3 = lse3(a3, a2, skip3 ? a1 : NEGF) + e.y;
                a0 = (act && v0) ? n0 : a0;
                a1 = (act && v1) ? n1 : a1;
                a2 = (act && v2) ? n2 : a2;
                a3 = (act && v3) ? n3 : a3;
            } else {
                float f0 = a0 + eb;
                float f1 = a1 + e.x;
                float f2 = a2 + eb;
                float f3 = a3 + e.y;
                float f0p = dpp_down1(f0, NEGF);
                float f1p = dpp_down1(f1, NEGF);
                float n0 = lse2(f0, f1);
                float n1 = lse3(f1, f2, skip3 ? f3 : NEGF);
                float n2 = lse2(f2, f3);
                float n3 = lse3(f3, f0p, skip5 ? f1p : NEGF);
                a0 = (act && v0) ? n0 : a0;
                a1 = (act && v1) ? n1 : a1;
                a2 = (act && v2) ? n2 : a2;
                a3 = (act && v3) ? n3 : a3;
            }
        }
    }

    *((float4*)strow + lane) = make_float4(a0, a1, a2, a3);
}

// tot_n = logsumexp_s( alpha[tm][s] + beta[tm][s] );  out += -tot_n if finite
__global__ __launch_bounds__(64, 1)
void ctc_combine(const float* __restrict__ state, float* __restrict__ out, int N)
{
    const int n = blockIdx.x;
    const int lane = threadIdx.x;
    const float4 A = *((const float4*)(state + (size_t)n * 256) + lane);
    const float4 B = *((const float4*)(state + (size_t)(N + n) * 256) + lane);
    float v = lse2(lse2(A.x + B.x, A.y + B.y), lse2(A.z + B.z, A.w + B.w));
    #pragma unroll
    for (int off = 1; off < 64; off <<= 1) {
        float o = __shfl_xor(v, off, 64);
        v = lse2(v, o);
    }
    if (lane == 0) {
        float tot = v * LN2F;
        if (tot > -1e29f) atomicAdd(out, -tot);
    }
}

extern "C" void kernel_launch(void* const* d_in, const int* in_sizes, int n_in,
                              void* d_out, int out_size, void* d_ws, size_t ws_size,
                              hipStream_t stream) {
    const float* lp      = (const float*)d_in[0];
    const int*   targets = (const int*)d_in[1];
    const int*   in_len  = (const int*)d_in[2];
    const int*   tgt_len = (const int*)d_in[3];
    const int N = in_sizes[2];
    const int L = in_sizes[1] / N;
    const int C = 1024;                       // fixed by the reference problem
    const int T = (int)((long)in_sizes[0] / ((long)N * C));

    float* out   = (float*)d_out;
    float* state = (float*)d_ws;              // [2N][256] floats = 64 KB
    const size_t state_bytes = (size_t)2 * N * 256 * sizeof(float);

    const int G = (T + 1) / 2;                // max serial steps per direction
    size_t avail = (ws_size > state_bytes) ? (ws_size - state_bytes) : 0;
    // per capacity-step per direction: N*(512 + 4) bytes
    int CRcap = (int)(avail / ((size_t)2 * N * 516));
    int CR = CRcap - (BLK + 8);               // padding so refill overruns stay in ws
    if (CR < 1) CR = 1;
    if (CR > G) { CR = G; CRcap = G + BLK + 8; }
    const int nsuper = (G + CR - 1) / CR;

    float2* em_f2 = (float2*)(state + (size_t)2 * N * 256);
    float2* em_b2 = em_f2 + (size_t)CRcap * N * 64;
    float*  eb_f  = (float*)(em_b2 + (size_t)CRcap * N * 64);
    float*  eb_b  = eb_f + (size_t)CRcap * N;

    hipMemsetAsync(out, 0, sizeof(float), stream);
    for (int c = 0; c < nsuper; ++c) {
        const int g0 = c * CR;
        int CRlen = G - g0; if (CRlen > CR) CRlen = CR;
        const int waves  = 2 * CRlen * N;
        const int blocks = (waves * 64 + 255) / 256;
        ctc_gather<<<blocks, 256, 0, stream>>>(lp, targets, in_len, tgt_len,
                                               em_f2, em_b2, eb_f, eb_b,
                                               g0, CRlen, CRcap, T, N, C, L);
        ctc_scan<<<2 * N, 64, 0, stream>>>(lp, targets, in_len, tgt_len,
                                           em_f2, em_b2, eb_f, eb_b, state,
                                           g0, CRlen, CRcap, (c == 0) ? 1 : 0, T, N, C, L);
    }
    ctc_combine<<<N, 64, 0, stream>>>(state, out, N);
}